// Round 1
// baseline (293583.228 us; speedup 1.0000x reference)
//
#include <hip/hip_runtime.h>
#include <hip/hip_bf16.h>

#define T_SEQ 10240
#define GRU_NWG 64

// ---------------- mel upsampling: fused repeat(scale) + SAME avg-conv ----------------
__global__ void upsample_kernel(const float* __restrict__ in, float* __restrict__ out,
                                const float* __restrict__ wk,
                                int B, int Tin, int Tout, int shift, int taps)
{
    int idx = blockIdx.x * blockDim.x + threadIdx.x;
    int total = B * Tout * 80;
    if (idx >= total) return;
    int m = idx % 80;
    int r = idx / 80;
    int t = r % Tout;
    int b = r / Tout;
    int s = taps >> 1;
    float acc = 0.f;
    for (int d = -s; d <= s; ++d) {
        int i = t + d;
        if (i >= 0 && i < Tout)
            acc += in[((size_t)b * Tin + (i >> shift)) * 80 + m] * wk[d + s];
    }
    out[idx] = acc;
}

// ---------------- conditioning net: conv0 (VALID, k=5) + BN + relu ----------------
__global__ __launch_bounds__(128) void conv0_kernel(
    const float* __restrict__ mels, const float* __restrict__ w,
    const float* __restrict__ g, const float* __restrict__ b,
    const float* __restrict__ m_, const float* __restrict__ v_,
    float* __restrict__ a)
{
    __shared__ float xin[400];
    int bt = blockIdx.x;              // 0..159
    int bb = bt / 40, t = bt % 40;
    int c = threadIdx.x;
    for (int idx = c; idx < 400; idx += 128)
        xin[idx] = mels[((size_t)bb * 44 + t + idx / 80) * 80 + (idx % 80)];
    __syncthreads();
    float s = 0.f;
    for (int q = 0; q < 400; ++q) s += xin[q] * w[q * 128 + c];
    s = (s - m_[c]) * rsqrtf(v_[c] + 1e-3f) * g[c] + b[c];
    a[bt * 128 + c] = fmaxf(s, 0.f);
}

// ---------------- one residual block: a += bn2(relu(bn1(a@W1))@W2) ----------------
__global__ __launch_bounds__(128) void resblock_kernel(
    const float* __restrict__ W1, const float* __restrict__ W2,
    const float* __restrict__ g1, const float* __restrict__ b1,
    const float* __restrict__ m1, const float* __restrict__ v1,
    const float* __restrict__ g2, const float* __restrict__ b2,
    const float* __restrict__ m2, const float* __restrict__ v2,
    float* __restrict__ a)
{
    __shared__ float ain[128], y1[128];
    int tok = blockIdx.x;
    int c = threadIdx.x;
    ain[c] = a[tok * 128 + c];
    __syncthreads();
    float s = 0.f;
    #pragma unroll 8
    for (int k = 0; k < 128; ++k) s += ain[k] * W1[k * 128 + c];
    s = (s - m1[c]) * rsqrtf(v1[c] + 1e-3f) * g1[c] + b1[c];
    y1[c] = fmaxf(s, 0.f);
    __syncthreads();
    float s2 = 0.f;
    #pragma unroll 8
    for (int k = 0; k < 128; ++k) s2 += y1[k] * W2[k * 128 + c];
    s2 = (s2 - m2[c]) * rsqrtf(v2[c] + 1e-3f) * g2[c] + b2[c];
    a[tok * 128 + c] = ain[c] + s2;
}

// ---------------- cond out matmul: a @ mr_out_w + mr_out_b ----------------
__global__ __launch_bounds__(128) void outmat_kernel(
    const float* __restrict__ W, const float* __restrict__ bias,
    const float* __restrict__ a, float* __restrict__ out)
{
    __shared__ float ain[128];
    int tok = blockIdx.x;
    int c = threadIdx.x;
    ain[c] = a[tok * 128 + c];
    __syncthreads();
    float s = 0.f;
    #pragma unroll 8
    for (int k = 0; k < 128; ++k) s += ain[k] * W[k * 128 + c];
    out[tok * 128 + c] = s + bias[c];
}

// ---------------- big fused GEMM ----------------
// modes: 0=Wi (K=113, gather audio/mels_up/a0, out f32 x)
//        1=Wx0 (K=512, out bf16 xp, bias2=bh cols<1024)
//        2=Wx1 (K=544 = x|a1, out bf16 xp, bias2=bh cols<1024)
//        3=Wd0 (K=544 = x|a2, epilogue relu+resid, out f32)
//        4=Wd1 (K=544 = x3|a3, epilogue relu+resid, out f32)
__device__ __forceinline__ float fetchA(int mode, int row, int k, int K,
    const float* audio, const float* melsup, const float* cond, const float* xA)
{
    if (k >= K) return 0.f;
    int b = row / T_SEQ;
    int t = row - b * T_SEQ;
    if (mode == 0) {
        if (k == 0) return audio[(size_t)b * (T_SEQ + 1) + t];
        if (k < 81) return melsup[((size_t)b * 11264 + 512 + t) * 80 + (k - 1)];
        return cond[((size_t)b * 40 + (t >> 8)) * 128 + (k - 81)];
    }
    if (k < 512) return xA[(size_t)row * 512 + k];
    int co = (mode == 2) ? 32 : (mode == 3) ? 64 : 96;
    return cond[((size_t)b * 40 + (t >> 8)) * 128 + co + (k - 512)];
}

__global__ __launch_bounds__(256) void gemm_big(
    int mode, int N, int K,
    const float* __restrict__ W, const float* __restrict__ bias1,
    const float* __restrict__ bias2,
    const float* __restrict__ audio, const float* __restrict__ melsup,
    const float* __restrict__ cond, const float* __restrict__ xA,
    const float* __restrict__ resid, float* __restrict__ outF,
    __hip_bfloat16* __restrict__ outB)
{
    __shared__ float As[16][68];
    __shared__ float Bs[16][68];
    const int tid = threadIdx.x;
    const int row0 = blockIdx.y * 64;
    const int col0 = blockIdx.x * 64;
    const int tx = tid & 15, ty = tid >> 4;
    float acc[4][4] = {};
    const int nkt = (K + 15) >> 4;
    for (int kt = 0; kt < nkt; ++kt) {
        const int kb = kt << 4;
        #pragma unroll
        for (int l = 0; l < 4; ++l) {
            int k = (tid >> 6) + l * 4;
            int m = tid & 63;
            As[k][m] = fetchA(mode, row0 + m, kb + k, K, audio, melsup, cond, xA);
            float bv = 0.f;
            if (kb + k < K) bv = W[(size_t)(kb + k) * N + col0 + m];
            Bs[k][m] = bv;
        }
        __syncthreads();
        #pragma unroll
        for (int k = 0; k < 16; ++k) {
            float a0 = As[k][(ty << 2) + 0], a1 = As[k][(ty << 2) + 1];
            float a2 = As[k][(ty << 2) + 2], a3 = As[k][(ty << 2) + 3];
            float b0 = Bs[k][(tx << 2) + 0], b1 = Bs[k][(tx << 2) + 1];
            float b2 = Bs[k][(tx << 2) + 2], b3 = Bs[k][(tx << 2) + 3];
            acc[0][0] += a0 * b0; acc[0][1] += a0 * b1; acc[0][2] += a0 * b2; acc[0][3] += a0 * b3;
            acc[1][0] += a1 * b0; acc[1][1] += a1 * b1; acc[1][2] += a1 * b2; acc[1][3] += a1 * b3;
            acc[2][0] += a2 * b0; acc[2][1] += a2 * b1; acc[2][2] += a2 * b2; acc[2][3] += a2 * b3;
            acc[3][0] += a3 * b0; acc[3][1] += a3 * b1; acc[3][2] += a3 * b2; acc[3][3] += a3 * b3;
        }
        __syncthreads();
    }
    #pragma unroll
    for (int i = 0; i < 4; ++i) {
        int row = row0 + (ty << 2) + i;
        #pragma unroll
        for (int jt = 0; jt < 4; ++jt) {
            int col = col0 + (tx << 2) + jt;
            float v = acc[i][jt] + bias1[col];
            if (bias2 && col < 1024) v += bias2[col];
            if (mode == 0) {
                outF[(size_t)row * N + col] = v;
            } else if (mode <= 2) {
                outB[(size_t)row * 1536 + col] = __float2bfloat16(v);
            } else {
                v = fmaxf(v, 0.f) + resid[(size_t)row * 512 + col];
                outF[(size_t)row * 512 + col] = v;
            }
        }
    }
}

// ---------------- persistent GRU layer ----------------
// 64 WGs x 512 threads. thread = (b:4, jj:8, part:16); each WG owns hidden j = wg*8..wg*8+7.
// Recurrent weights in registers (96 f32/thread). h ping-pong in global (L2-hot).
// xp (bf16) already contains x@Wx + bx (+ bh for z/r gate columns only).
__global__ __launch_bounds__(512) void gru_layer(
    const float* __restrict__ Wh,             // (512,1536)
    const float* __restrict__ bh,             // (1536) - only [1024:1536) used here
    const __hip_bfloat16* __restrict__ xp,    // (B*T,1536)
    float* __restrict__ xio,                  // (B*T,512) in: x, out: h+x
    float* __restrict__ hbuf,                 // (2,B,512) zeroed
    int* __restrict__ bar,                    // zeroed
    int T)
{
    const int tid = threadIdx.x;
    const int w = blockIdx.x;
    const int b = tid >> 7;
    const int jj = (tid >> 4) & 7;
    const int part = tid & 15;
    const int j = w * 8 + jj;
    const int k0 = part * 32;

    float wz[32], wr[32], wh3[32];
    #pragma unroll
    for (int i = 0; i < 32; ++i) {
        const float* rowp = Wh + (size_t)(k0 + i) * 1536;
        wz[i]  = rowp[j];
        wr[i]  = rowp[512 + j];
        wh3[i] = rowp[1024 + j];
    }
    const float bhh = bh[1024 + j];

    for (int t = 0; t < T; ++t) {
        const float* hin = hbuf + (t & 1) * 2048;
        float* hout = hbuf + ((t + 1) & 1) * 2048;
        const float* hp = hin + b * 512 + k0;
        float az = 0.f, ar = 0.f, ah = 0.f;
        #pragma unroll
        for (int i = 0; i < 32; i += 4) {
            float4 hv = *reinterpret_cast<const float4*>(hp + i);
            az += hv.x * wz[i] + hv.y * wz[i + 1] + hv.z * wz[i + 2] + hv.w * wz[i + 3];
            ar += hv.x * wr[i] + hv.y * wr[i + 1] + hv.z * wr[i + 2] + hv.w * wr[i + 3];
            ah += hv.x * wh3[i] + hv.y * wh3[i + 1] + hv.z * wh3[i + 2] + hv.w * wh3[i + 3];
        }
        #pragma unroll
        for (int d = 8; d; d >>= 1) {
            az += __shfl_down(az, d, 16);
            ar += __shfl_down(ar, d, 16);
            ah += __shfl_down(ah, d, 16);
        }
        if (part == 0) {
            const __hip_bfloat16* xpt = xp + ((size_t)b * T + t) * 1536;
            float xz = __bfloat162float(xpt[j]);
            float xr = __bfloat162float(xpt[512 + j]);
            float xh = __bfloat162float(xpt[1024 + j]);
            float z = 1.f / (1.f + expf(-(xz + az)));
            float r = 1.f / (1.f + expf(-(xr + ar)));
            float hh = tanhf(xh + r * (ah + bhh));
            float hprev = hin[b * 512 + j];
            float hn = z * hprev + (1.f - z) * hh;
            hout[b * 512 + j] = hn;
            size_t xi = ((size_t)b * T + t) * 512 + j;
            xio[xi] += hn;
        }
        __threadfence();
        __syncthreads();
        if (tid == 0) {
            __hip_atomic_fetch_add(bar, 1, __ATOMIC_ACQ_REL, __HIP_MEMORY_SCOPE_AGENT);
            const int target = (t + 1) * GRU_NWG;
            while (__hip_atomic_load(bar, __ATOMIC_ACQUIRE, __HIP_MEMORY_SCOPE_AGENT) < target) {}
        }
        __syncthreads();
    }
}

// ---------------- final projection: logits = x @ Wp + bp ----------------
__global__ __launch_bounds__(256) void wp_kernel(
    const float* __restrict__ x, const float* __restrict__ Wp,
    const float* __restrict__ bp, float* __restrict__ out)
{
    int r = threadIdx.x >> 5, c = threadIdx.x & 31;
    size_t row = (size_t)blockIdx.x * 8 + r;
    if (c >= 30) return;
    const float* xr = x + row * 512;
    float acc = 0.f;
    #pragma unroll 8
    for (int k = 0; k < 512; ++k) acc += xr[k] * Wp[k * 30 + c];
    out[row * 30 + c] = acc + bp[c];
}

extern "C" void kernel_launch(void* const* d_in, const int* in_sizes, int n_in,
                              void* d_out, int out_size, void* d_ws, size_t ws_size,
                              hipStream_t stream)
{
    const float* audios = (const float*)d_in[0];
    const float* mels   = (const float*)d_in[1];
    const float* w_mel0 = (const float*)d_in[2];
    const float* w_mel1 = (const float*)d_in[3];
    const float* w_mel2 = (const float*)d_in[4];
    const float* conv0w = (const float*)d_in[5];
    const float* bn0g = (const float*)d_in[6];
    const float* bn0b = (const float*)d_in[7];
    const float* bn0m = (const float*)d_in[8];
    const float* bn0v = (const float*)d_in[9];
    const float* r_w1   = (const float*)d_in[10];
    const float* r_bn1g = (const float*)d_in[11];
    const float* r_bn1b = (const float*)d_in[12];
    const float* r_bn1m = (const float*)d_in[13];
    const float* r_bn1v = (const float*)d_in[14];
    const float* r_w2   = (const float*)d_in[15];
    const float* r_bn2g = (const float*)d_in[16];
    const float* r_bn2b = (const float*)d_in[17];
    const float* r_bn2m = (const float*)d_in[18];
    const float* r_bn2v = (const float*)d_in[19];
    const float* mr_out_w = (const float*)d_in[20];
    const float* mr_out_b = (const float*)d_in[21];
    const float* Wi = (const float*)d_in[22];
    const float* bi = (const float*)d_in[23];
    const float* Wx0 = (const float*)d_in[24];
    const float* Wh0 = (const float*)d_in[25];
    const float* bx0 = (const float*)d_in[26];
    const float* bh0 = (const float*)d_in[27];
    const float* Wx1 = (const float*)d_in[28];
    const float* Wh1 = (const float*)d_in[29];
    const float* bx1 = (const float*)d_in[30];
    const float* bh1 = (const float*)d_in[31];
    const float* Wd0 = (const float*)d_in[32];
    const float* bd0 = (const float*)d_in[33];
    const float* Wd1 = (const float*)d_in[34];
    const float* bd1 = (const float*)d_in[35];
    const float* Wp = (const float*)d_in[36];
    const float* bp = (const float*)d_in[37];

    char* ws = (char*)d_ws;
    size_t off = 0;
    auto alloc = [&](size_t n) { size_t r = off; off += (n + 255) & ~(size_t)255; return r; };
    const size_t M = 4 * (size_t)T_SEQ;                      // 40960
    size_t xp_off = alloc(M * 1536 * 2);                     // bf16 xp; reused as f32 x3
    size_t x_off  = alloc(M * 512 * 4);                      // f32 x
    size_t s1_off = alloc((size_t)4 * 176 * 80 * 4);
    size_t s2_off = alloc((size_t)4 * 1408 * 80 * 4);
    size_t s3_off = alloc((size_t)4 * 11264 * 80 * 4);
    size_t ca_off = alloc((size_t)160 * 128 * 4);
    size_t cf_off = alloc((size_t)160 * 128 * 4);
    size_t hb_off = alloc(16384 + 256);

    __hip_bfloat16* xp = (__hip_bfloat16*)(ws + xp_off);
    float* x3   = (float*)(ws + xp_off);
    float* xbuf = (float*)(ws + x_off);
    float* st1  = (float*)(ws + s1_off);
    float* st2  = (float*)(ws + s2_off);
    float* st3  = (float*)(ws + s3_off);
    float* conda = (float*)(ws + ca_off);
    float* condf = (float*)(ws + cf_off);
    float* hbuf = (float*)(ws + hb_off);
    int* bar = (int*)(ws + hb_off + 16384);
    float* outp = (float*)d_out;

    // 1-3: mel upsampling
    {
        int tot1 = 4 * 176 * 80;
        upsample_kernel<<<(tot1 + 255) / 256, 256, 0, stream>>>(mels, st1, w_mel0, 4, 44, 176, 2, 9);
        int tot2 = 4 * 1408 * 80;
        upsample_kernel<<<(tot2 + 255) / 256, 256, 0, stream>>>(st1, st2, w_mel1, 4, 176, 1408, 3, 17);
        int tot3 = 4 * 11264 * 80;
        upsample_kernel<<<(tot3 + 255) / 256, 256, 0, stream>>>(st2, st3, w_mel2, 4, 1408, 11264, 3, 17);
    }
    // 4-6: conditioning net
    conv0_kernel<<<160, 128, 0, stream>>>(mels, conv0w, bn0g, bn0b, bn0m, bn0v, conda);
    for (int i = 0; i < 10; ++i) {
        resblock_kernel<<<160, 128, 0, stream>>>(
            r_w1 + (size_t)i * 128 * 128, r_w2 + (size_t)i * 128 * 128,
            r_bn1g + i * 128, r_bn1b + i * 128, r_bn1m + i * 128, r_bn1v + i * 128,
            r_bn2g + i * 128, r_bn2b + i * 128, r_bn2m + i * 128, r_bn2v + i * 128,
            conda);
    }
    outmat_kernel<<<160, 128, 0, stream>>>(mr_out_w, mr_out_b, conda, condf);

    dim3 blk(256);
    // 7: x = concat(audio, mels_up, a0) @ Wi + bi
    gemm_big<<<dim3(8, 640), blk, 0, stream>>>(0, 512, 113, Wi, bi, nullptr,
        audios, st3, condf, nullptr, nullptr, xbuf, nullptr);
    // 8: xp0 = x @ Wx0 + bx0 (+bh0 z/r)
    gemm_big<<<dim3(24, 640), blk, 0, stream>>>(1, 1536, 512, Wx0, bx0, bh0,
        nullptr, nullptr, condf, xbuf, nullptr, nullptr, xp);
    // 9: GRU0
    hipMemsetAsync(ws + hb_off, 0, 16384 + 256, stream);
    gru_layer<<<GRU_NWG, 512, 0, stream>>>(Wh0, bh0, xp, xbuf, hbuf, bar, T_SEQ);
    // 10: xp1 = concat(x1, a1) @ Wx1 + bx1 (+bh1 z/r)
    gemm_big<<<dim3(24, 640), blk, 0, stream>>>(2, 1536, 544, Wx1, bx1, bh1,
        nullptr, nullptr, condf, xbuf, nullptr, nullptr, xp);
    // 11: GRU1
    hipMemsetAsync(ws + hb_off, 0, 16384 + 256, stream);
    gru_layer<<<GRU_NWG, 512, 0, stream>>>(Wh1, bh1, xp, xbuf, hbuf, bar, T_SEQ);
    // 12: x3 = relu(concat(x2, a2) @ Wd0 + bd0) + x2
    gemm_big<<<dim3(8, 640), blk, 0, stream>>>(3, 512, 544, Wd0, bd0, nullptr,
        nullptr, nullptr, condf, xbuf, xbuf, x3, nullptr);
    // 13: x4 = relu(concat(x3, a3) @ Wd1 + bd1) + x3
    gemm_big<<<dim3(8, 640), blk, 0, stream>>>(4, 512, 544, Wd1, bd1, nullptr,
        nullptr, nullptr, condf, x3, x3, xbuf, nullptr);
    // 14: logits
    wp_kernel<<<5120, 256, 0, stream>>>(xbuf, Wp, bp, outp);
}

// Round 2
// 125224.072 us; speedup vs baseline: 2.3445x; 2.3445x over previous
//
#include <hip/hip_runtime.h>
#include <hip/hip_bf16.h>

#define T_SEQ 10240
#define GRU_NWG 64

// ---------------- mel upsampling: fused repeat(scale) + SAME avg-conv ----------------
__global__ void upsample_kernel(const float* __restrict__ in, float* __restrict__ out,
                                const float* __restrict__ wk,
                                int B, int Tin, int Tout, int shift, int taps)
{
    int idx = blockIdx.x * blockDim.x + threadIdx.x;
    int total = B * Tout * 80;
    if (idx >= total) return;
    int m = idx % 80;
    int r = idx / 80;
    int t = r % Tout;
    int b = r / Tout;
    int s = taps >> 1;
    float acc = 0.f;
    for (int d = -s; d <= s; ++d) {
        int i = t + d;
        if (i >= 0 && i < Tout)
            acc += in[((size_t)b * Tin + (i >> shift)) * 80 + m] * wk[d + s];
    }
    out[idx] = acc;
}

// ---------------- conditioning net: conv0 (VALID, k=5) + BN + relu ----------------
__global__ __launch_bounds__(128) void conv0_kernel(
    const float* __restrict__ mels, const float* __restrict__ w,
    const float* __restrict__ g, const float* __restrict__ b,
    const float* __restrict__ m_, const float* __restrict__ v_,
    float* __restrict__ a)
{
    __shared__ float xin[400];
    int bt = blockIdx.x;              // 0..159
    int bb = bt / 40, t = bt % 40;
    int c = threadIdx.x;
    for (int idx = c; idx < 400; idx += 128)
        xin[idx] = mels[((size_t)bb * 44 + t + idx / 80) * 80 + (idx % 80)];
    __syncthreads();
    float s = 0.f;
    for (int q = 0; q < 400; ++q) s += xin[q] * w[q * 128 + c];
    s = (s - m_[c]) * rsqrtf(v_[c] + 1e-3f) * g[c] + b[c];
    a[bt * 128 + c] = fmaxf(s, 0.f);
}

// ---------------- one residual block: a += bn2(relu(bn1(a@W1))@W2) ----------------
__global__ __launch_bounds__(128) void resblock_kernel(
    const float* __restrict__ W1, const float* __restrict__ W2,
    const float* __restrict__ g1, const float* __restrict__ b1,
    const float* __restrict__ m1, const float* __restrict__ v1,
    const float* __restrict__ g2, const float* __restrict__ b2,
    const float* __restrict__ m2, const float* __restrict__ v2,
    float* __restrict__ a)
{
    __shared__ float ain[128], y1[128];
    int tok = blockIdx.x;
    int c = threadIdx.x;
    ain[c] = a[tok * 128 + c];
    __syncthreads();
    float s = 0.f;
    #pragma unroll 8
    for (int k = 0; k < 128; ++k) s += ain[k] * W1[k * 128 + c];
    s = (s - m1[c]) * rsqrtf(v1[c] + 1e-3f) * g1[c] + b1[c];
    y1[c] = fmaxf(s, 0.f);
    __syncthreads();
    float s2 = 0.f;
    #pragma unroll 8
    for (int k = 0; k < 128; ++k) s2 += y1[k] * W2[k * 128 + c];
    s2 = (s2 - m2[c]) * rsqrtf(v2[c] + 1e-3f) * g2[c] + b2[c];
    a[tok * 128 + c] = ain[c] + s2;
}

// ---------------- cond out matmul: a @ mr_out_w + mr_out_b ----------------
__global__ __launch_bounds__(128) void outmat_kernel(
    const float* __restrict__ W, const float* __restrict__ bias,
    const float* __restrict__ a, float* __restrict__ out)
{
    __shared__ float ain[128];
    int tok = blockIdx.x;
    int c = threadIdx.x;
    ain[c] = a[tok * 128 + c];
    __syncthreads();
    float s = 0.f;
    #pragma unroll 8
    for (int k = 0; k < 128; ++k) s += ain[k] * W[k * 128 + c];
    out[tok * 128 + c] = s + bias[c];
}

// ---------------- big fused GEMM ----------------
// modes: 0=Wi (K=113, gather audio/mels_up/a0, out f32 x)
//        1=Wx0 (K=512, out bf16 xp, bias2=bh cols<1024)
//        2=Wx1 (K=544 = x|a1, out bf16 xp, bias2=bh cols<1024)
//        3=Wd0 (K=544 = x|a2, epilogue relu+resid, out f32)
//        4=Wd1 (K=544 = x3|a3, epilogue relu+resid, out f32)
__device__ __forceinline__ float fetchA(int mode, int row, int k, int K,
    const float* audio, const float* melsup, const float* cond, const float* xA)
{
    if (k >= K) return 0.f;
    int b = row / T_SEQ;
    int t = row - b * T_SEQ;
    if (mode == 0) {
        if (k == 0) return audio[(size_t)b * (T_SEQ + 1) + t];
        if (k < 81) return melsup[((size_t)b * 11264 + 512 + t) * 80 + (k - 1)];
        return cond[((size_t)b * 40 + (t >> 8)) * 128 + (k - 81)];
    }
    if (k < 512) return xA[(size_t)row * 512 + k];
    int co = (mode == 2) ? 32 : (mode == 3) ? 64 : 96;
    return cond[((size_t)b * 40 + (t >> 8)) * 128 + co + (k - 512)];
}

__global__ __launch_bounds__(256) void gemm_big(
    int mode, int N, int K,
    const float* __restrict__ W, const float* __restrict__ bias1,
    const float* __restrict__ bias2,
    const float* __restrict__ audio, const float* __restrict__ melsup,
    const float* __restrict__ cond, const float* __restrict__ xA,
    const float* __restrict__ resid, float* __restrict__ outF,
    __hip_bfloat16* __restrict__ outB)
{
    __shared__ float As[16][68];
    __shared__ float Bs[16][68];
    const int tid = threadIdx.x;
    const int row0 = blockIdx.y * 64;
    const int col0 = blockIdx.x * 64;
    const int tx = tid & 15, ty = tid >> 4;
    float acc[4][4] = {};
    const int nkt = (K + 15) >> 4;
    for (int kt = 0; kt < nkt; ++kt) {
        const int kb = kt << 4;
        #pragma unroll
        for (int l = 0; l < 4; ++l) {
            int k = (tid >> 6) + l * 4;
            int m = tid & 63;
            float bv = 0.f;
            if (kb + k < K) bv = W[(size_t)(kb + k) * N + col0 + m];
            Bs[k][m] = bv;
        }
        if (mode != 0) {
            // coalesced float4 A staging (x region, k<512); scalar fallback for cond tail
            int m = tid >> 2, kq = tid & 3;
            int row = row0 + m;
            int k = kb + kq * 4;
            if (k + 3 < 512) {
                float4 v = *reinterpret_cast<const float4*>(xA + (size_t)row * 512 + k);
                As[kq * 4 + 0][m] = v.x; As[kq * 4 + 1][m] = v.y;
                As[kq * 4 + 2][m] = v.z; As[kq * 4 + 3][m] = v.w;
            } else {
                #pragma unroll
                for (int i = 0; i < 4; ++i)
                    As[kq * 4 + i][m] = fetchA(mode, row, k + i, K, audio, melsup, cond, xA);
            }
        } else {
            #pragma unroll
            for (int l = 0; l < 4; ++l) {
                int k = (tid >> 6) + l * 4;
                int m = tid & 63;
                As[k][m] = fetchA(0, row0 + m, kb + k, K, audio, melsup, cond, xA);
            }
        }
        __syncthreads();
        #pragma unroll
        for (int k = 0; k < 16; ++k) {
            float a0 = As[k][(ty << 2) + 0], a1 = As[k][(ty << 2) + 1];
            float a2 = As[k][(ty << 2) + 2], a3 = As[k][(ty << 2) + 3];
            float b0 = Bs[k][(tx << 2) + 0], b1 = Bs[k][(tx << 2) + 1];
            float b2 = Bs[k][(tx << 2) + 2], b3 = Bs[k][(tx << 2) + 3];
            acc[0][0] += a0 * b0; acc[0][1] += a0 * b1; acc[0][2] += a0 * b2; acc[0][3] += a0 * b3;
            acc[1][0] += a1 * b0; acc[1][1] += a1 * b1; acc[1][2] += a1 * b2; acc[1][3] += a1 * b3;
            acc[2][0] += a2 * b0; acc[2][1] += a2 * b1; acc[2][2] += a2 * b2; acc[2][3] += a2 * b3;
            acc[3][0] += a3 * b0; acc[3][1] += a3 * b1; acc[3][2] += a3 * b2; acc[3][3] += a3 * b3;
        }
        __syncthreads();
    }
    #pragma unroll
    for (int i = 0; i < 4; ++i) {
        int row = row0 + (ty << 2) + i;
        #pragma unroll
        for (int jt = 0; jt < 4; ++jt) {
            int col = col0 + (tx << 2) + jt;
            float v = acc[i][jt] + bias1[col];
            if (bias2 && col < 1024) v += bias2[col];
            if (mode == 0) {
                outF[(size_t)row * N + col] = v;
            } else if (mode <= 2) {
                outB[(size_t)row * 1536 + col] = __float2bfloat16(v);
            } else {
                v = fmaxf(v, 0.f) + resid[(size_t)row * 512 + col];
                outF[(size_t)row * 512 + col] = v;
            }
        }
    }
}

// ---------------- persistent GRU layer ----------------
// 64 WGs x 512 threads. thread = (b:4, jj:8, part:16); WG owns hidden j = wg*8..wg*8+7.
// Recurrent weights in registers (96 f32/thread, launch_bounds(512,1) so no spill).
// Cross-WG h traffic via agent-scope relaxed atomics (sc1: L3-coherent, no L2 nukes).
// Barrier = distributed per-WG flags (64B apart) + one-wave 64-lane poll.
// xp/xio for step t+1 prefetched during step t.
__global__ __launch_bounds__(512, 1) void gru_layer(
    const float* __restrict__ Wh,             // (512,1536)
    const float* __restrict__ bh,             // (1536) - only [1024:1536) used here
    const __hip_bfloat16* __restrict__ xp,    // (B*T,1536)  x@Wx+bx (+bh for z/r cols)
    float* __restrict__ xio,                  // (B*T,512) in: x, out: x+h
    float* __restrict__ hbuf,                 // (2,B,512) zeroed
    int* __restrict__ flags,                  // 64 flags, 64B apart, zeroed
    int T)
{
    const int tid = threadIdx.x;
    const int w = blockIdx.x;
    const int b = tid >> 7;
    const int jj = (tid >> 4) & 7;
    const int part = tid & 15;
    const int j = w * 8 + jj;
    const int k0 = part * 32;
    const bool lead = (part == 0);

    float wz[32], wr[32], wh3[32];
    #pragma unroll
    for (int i = 0; i < 32; ++i) {
        const float* rowp = Wh + (size_t)(k0 + i) * 1536;
        wz[i]  = rowp[j];
        wr[i]  = rowp[512 + j];
        wh3[i] = rowp[1024 + j];
    }
    const float bhh = bh[1024 + j];

    // prefetch t=0 gate inputs
    float xz_c = 0.f, xr_c = 0.f, xh_c = 0.f, xv_c = 0.f;
    if (lead) {
        const __hip_bfloat16* p = xp + (size_t)b * T * 1536;
        xz_c = __bfloat162float(p[j]);
        xr_c = __bfloat162float(p[512 + j]);
        xh_c = __bfloat162float(p[1024 + j]);
        xv_c = xio[(size_t)b * T * 512 + j];
    }

    for (int t = 0; t < T; ++t) {
        const float* hin = hbuf + (t & 1) * 2048;
        float* hout = hbuf + ((t + 1) & 1) * 2048;

        // load h slice from L3 (agent-scope relaxed: sc1, no cache invalidation)
        float hreg[32];
        const unsigned long long* hp8 =
            (const unsigned long long*)(hin + b * 512 + k0);
        #pragma unroll
        for (int i = 0; i < 16; ++i) {
            unsigned long long u = __hip_atomic_load(hp8 + i, __ATOMIC_RELAXED,
                                                     __HIP_MEMORY_SCOPE_AGENT);
            hreg[2 * i]     = __uint_as_float((unsigned)(u & 0xffffffffull));
            hreg[2 * i + 1] = __uint_as_float((unsigned)(u >> 32));
        }
        float hprev = 0.f;
        if (lead)
            hprev = __hip_atomic_load(hin + b * 512 + j, __ATOMIC_RELAXED,
                                      __HIP_MEMORY_SCOPE_AGENT);

        // prefetch next step's gate inputs (hides HBM latency under compute+barrier)
        float xz_n = 0.f, xr_n = 0.f, xh_n = 0.f, xv_n = 0.f;
        if (lead && t + 1 < T) {
            const __hip_bfloat16* p = xp + ((size_t)b * T + t + 1) * 1536;
            xz_n = __bfloat162float(p[j]);
            xr_n = __bfloat162float(p[512 + j]);
            xh_n = __bfloat162float(p[1024 + j]);
            xv_n = xio[((size_t)b * T + t + 1) * 512 + j];
        }

        float az = 0.f, ar = 0.f, ah = 0.f;
        #pragma unroll
        for (int i = 0; i < 32; ++i) {
            az += hreg[i] * wz[i];
            ar += hreg[i] * wr[i];
            ah += hreg[i] * wh3[i];
        }
        #pragma unroll
        for (int d = 8; d; d >>= 1) {
            az += __shfl_down(az, d, 16);
            ar += __shfl_down(ar, d, 16);
            ah += __shfl_down(ah, d, 16);
        }

        if (lead) {
            float z = 1.f / (1.f + __expf(-(xz_c + az)));
            float r = 1.f / (1.f + __expf(-(xr_c + ar)));
            float e2 = __expf(-2.f * (xh_c + r * (ah + bhh)));
            float hh = (1.f - e2) / (1.f + e2);
            float hn = z * hprev + (1.f - z) * hh;
            __hip_atomic_store(hout + b * 512 + j, hn, __ATOMIC_RELAXED,
                               __HIP_MEMORY_SCOPE_AGENT);
            xio[((size_t)b * T + t) * 512 + j] = xv_c + hn;
        }
        xz_c = xz_n; xr_c = xr_n; xh_c = xh_n; xv_c = xv_n;

        // ---- distributed barrier ----
        asm volatile("s_waitcnt vmcnt(0)" ::: "memory");  // h stores at L3
        __builtin_amdgcn_s_barrier();                     // all waves of WG done
        if (tid == 0)
            __hip_atomic_store(flags + w * 16, t + 1, __ATOMIC_RELAXED,
                               __HIP_MEMORY_SCOPE_AGENT);
        if (tid < 64) {
            // wave 0: lane L polls WG L's flag; exec-mask loop exits when all 64 ready
            while (__hip_atomic_load(flags + tid * 16, __ATOMIC_RELAXED,
                                     __HIP_MEMORY_SCOPE_AGENT) < t + 1) {}
        }
        __builtin_amdgcn_s_barrier();
    }
}

// ---------------- final projection: logits = x @ Wp + bp ----------------
__global__ __launch_bounds__(256) void wp_kernel(
    const float* __restrict__ x, const float* __restrict__ Wp,
    const float* __restrict__ bp, float* __restrict__ out)
{
    int r = threadIdx.x >> 5, c = threadIdx.x & 31;
    size_t row = (size_t)blockIdx.x * 8 + r;
    if (c >= 30) return;
    const float* xr = x + row * 512;
    float acc = 0.f;
    #pragma unroll 8
    for (int k = 0; k < 512; ++k) acc += xr[k] * Wp[k * 30 + c];
    out[row * 30 + c] = acc + bp[c];
}

extern "C" void kernel_launch(void* const* d_in, const int* in_sizes, int n_in,
                              void* d_out, int out_size, void* d_ws, size_t ws_size,
                              hipStream_t stream)
{
    const float* audios = (const float*)d_in[0];
    const float* mels   = (const float*)d_in[1];
    const float* w_mel0 = (const float*)d_in[2];
    const float* w_mel1 = (const float*)d_in[3];
    const float* w_mel2 = (const float*)d_in[4];
    const float* conv0w = (const float*)d_in[5];
    const float* bn0g = (const float*)d_in[6];
    const float* bn0b = (const float*)d_in[7];
    const float* bn0m = (const float*)d_in[8];
    const float* bn0v = (const float*)d_in[9];
    const float* r_w1   = (const float*)d_in[10];
    const float* r_bn1g = (const float*)d_in[11];
    const float* r_bn1b = (const float*)d_in[12];
    const float* r_bn1m = (const float*)d_in[13];
    const float* r_bn1v = (const float*)d_in[14];
    const float* r_w2   = (const float*)d_in[15];
    const float* r_bn2g = (const float*)d_in[16];
    const float* r_bn2b = (const float*)d_in[17];
    const float* r_bn2m = (const float*)d_in[18];
    const float* r_bn2v = (const float*)d_in[19];
    const float* mr_out_w = (const float*)d_in[20];
    const float* mr_out_b = (const float*)d_in[21];
    const float* Wi = (const float*)d_in[22];
    const float* bi = (const float*)d_in[23];
    const float* Wx0 = (const float*)d_in[24];
    const float* Wh0 = (const float*)d_in[25];
    const float* bx0 = (const float*)d_in[26];
    const float* bh0 = (const float*)d_in[27];
    const float* Wx1 = (const float*)d_in[28];
    const float* Wh1 = (const float*)d_in[29];
    const float* bx1 = (const float*)d_in[30];
    const float* bh1 = (const float*)d_in[31];
    const float* Wd0 = (const float*)d_in[32];
    const float* bd0 = (const float*)d_in[33];
    const float* Wd1 = (const float*)d_in[34];
    const float* bd1 = (const float*)d_in[35];
    const float* Wp = (const float*)d_in[36];
    const float* bp = (const float*)d_in[37];

    char* ws = (char*)d_ws;
    size_t off = 0;
    auto alloc = [&](size_t n) { size_t r = off; off += (n + 255) & ~(size_t)255; return r; };
    const size_t M = 4 * (size_t)T_SEQ;                      // 40960
    size_t xp_off = alloc(M * 1536 * 2);                     // bf16 xp; reused as f32 x3
    size_t x_off  = alloc(M * 512 * 4);                      // f32 x
    size_t s1_off = alloc((size_t)4 * 176 * 80 * 4);
    size_t s2_off = alloc((size_t)4 * 1408 * 80 * 4);
    size_t s3_off = alloc((size_t)4 * 11264 * 80 * 4);
    size_t ca_off = alloc((size_t)160 * 128 * 4);
    size_t cf_off = alloc((size_t)160 * 128 * 4);
    size_t hb_off = alloc(16384 + 4096);                     // hbuf + flags

    __hip_bfloat16* xp = (__hip_bfloat16*)(ws + xp_off);
    float* x3   = (float*)(ws + xp_off);
    float* xbuf = (float*)(ws + x_off);
    float* st1  = (float*)(ws + s1_off);
    float* st2  = (float*)(ws + s2_off);
    float* st3  = (float*)(ws + s3_off);
    float* conda = (float*)(ws + ca_off);
    float* condf = (float*)(ws + cf_off);
    float* hbuf = (float*)(ws + hb_off);
    int* flags = (int*)(ws + hb_off + 16384);
    float* outp = (float*)d_out;

    // 1-3: mel upsampling
    {
        int tot1 = 4 * 176 * 80;
        upsample_kernel<<<(tot1 + 255) / 256, 256, 0, stream>>>(mels, st1, w_mel0, 4, 44, 176, 2, 9);
        int tot2 = 4 * 1408 * 80;
        upsample_kernel<<<(tot2 + 255) / 256, 256, 0, stream>>>(st1, st2, w_mel1, 4, 176, 1408, 3, 17);
        int tot3 = 4 * 11264 * 80;
        upsample_kernel<<<(tot3 + 255) / 256, 256, 0, stream>>>(st2, st3, w_mel2, 4, 1408, 11264, 3, 17);
    }
    // 4-6: conditioning net
    conv0_kernel<<<160, 128, 0, stream>>>(mels, conv0w, bn0g, bn0b, bn0m, bn0v, conda);
    for (int i = 0; i < 10; ++i) {
        resblock_kernel<<<160, 128, 0, stream>>>(
            r_w1 + (size_t)i * 128 * 128, r_w2 + (size_t)i * 128 * 128,
            r_bn1g + i * 128, r_bn1b + i * 128, r_bn1m + i * 128, r_bn1v + i * 128,
            r_bn2g + i * 128, r_bn2b + i * 128, r_bn2m + i * 128, r_bn2v + i * 128,
            conda);
    }
    outmat_kernel<<<160, 128, 0, stream>>>(mr_out_w, mr_out_b, conda, condf);

    dim3 blk(256);
    // 7: x = concat(audio, mels_up, a0) @ Wi + bi
    gemm_big<<<dim3(8, 640), blk, 0, stream>>>(0, 512, 113, Wi, bi, nullptr,
        audios, st3, condf, nullptr, nullptr, xbuf, nullptr);
    // 8: xp0 = x @ Wx0 + bx0 (+bh0 z/r)
    gemm_big<<<dim3(24, 640), blk, 0, stream>>>(1, 1536, 512, Wx0, bx0, bh0,
        nullptr, nullptr, condf, xbuf, nullptr, nullptr, xp);
    // 9: GRU0
    hipMemsetAsync(ws + hb_off, 0, 16384 + 4096, stream);
    gru_layer<<<GRU_NWG, 512, 0, stream>>>(Wh0, bh0, xp, xbuf, hbuf, flags, T_SEQ);
    // 10: xp1 = concat(x1, a1) @ Wx1 + bx1 (+bh1 z/r)
    gemm_big<<<dim3(24, 640), blk, 0, stream>>>(2, 1536, 544, Wx1, bx1, bh1,
        nullptr, nullptr, condf, xbuf, nullptr, nullptr, xp);
    // 11: GRU1
    hipMemsetAsync(ws + hb_off, 0, 16384 + 4096, stream);
    gru_layer<<<GRU_NWG, 512, 0, stream>>>(Wh1, bh1, xp, xbuf, hbuf, flags, T_SEQ);
    // 12: x3 = relu(concat(x2, a2) @ Wd0 + bd0) + x2
    gemm_big<<<dim3(8, 640), blk, 0, stream>>>(3, 512, 544, Wd0, bd0, nullptr,
        nullptr, nullptr, condf, xbuf, xbuf, x3, nullptr);
    // 13: x4 = relu(concat(x3, a3) @ Wd1 + bd1) + x3
    gemm_big<<<dim3(8, 640), blk, 0, stream>>>(4, 512, 544, Wd1, bd1, nullptr,
        nullptr, nullptr, condf, x3, x3, xbuf, nullptr);
    // 14: logits
    wp_kernel<<<5120, 256, 0, stream>>>(xbuf, Wp, bp, outp);
}

// Round 3
// 94508.185 us; speedup vs baseline: 3.1064x; 1.3250x over previous
//
#include <hip/hip_runtime.h>
#include <hip/hip_bf16.h>

#define T_SEQ 10240
#define GRU_NWG 64

// ---------------- mel upsampling: fused repeat(scale) + SAME avg-conv ----------------
__global__ void upsample_kernel(const float* __restrict__ in, float* __restrict__ out,
                                const float* __restrict__ wk,
                                int B, int Tin, int Tout, int shift, int taps)
{
    int idx = blockIdx.x * blockDim.x + threadIdx.x;
    int total = B * Tout * 80;
    if (idx >= total) return;
    int m = idx % 80;
    int r = idx / 80;
    int t = r % Tout;
    int b = r / Tout;
    int s = taps >> 1;
    float acc = 0.f;
    for (int d = -s; d <= s; ++d) {
        int i = t + d;
        if (i >= 0 && i < Tout)
            acc += in[((size_t)b * Tin + (i >> shift)) * 80 + m] * wk[d + s];
    }
    out[idx] = acc;
}

// ---------------- conditioning net: conv0 (VALID, k=5) + BN + relu ----------------
__global__ __launch_bounds__(128) void conv0_kernel(
    const float* __restrict__ mels, const float* __restrict__ w,
    const float* __restrict__ g, const float* __restrict__ b,
    const float* __restrict__ m_, const float* __restrict__ v_,
    float* __restrict__ a)
{
    __shared__ float xin[400];
    int bt = blockIdx.x;              // 0..159
    int bb = bt / 40, t = bt % 40;
    int c = threadIdx.x;
    for (int idx = c; idx < 400; idx += 128)
        xin[idx] = mels[((size_t)bb * 44 + t + idx / 80) * 80 + (idx % 80)];
    __syncthreads();
    float s = 0.f;
    for (int q = 0; q < 400; ++q) s += xin[q] * w[q * 128 + c];
    s = (s - m_[c]) * rsqrtf(v_[c] + 1e-3f) * g[c] + b[c];
    a[bt * 128 + c] = fmaxf(s, 0.f);
}

// ---------------- one residual block: a += bn2(relu(bn1(a@W1))@W2) ----------------
__global__ __launch_bounds__(128) void resblock_kernel(
    const float* __restrict__ W1, const float* __restrict__ W2,
    const float* __restrict__ g1, const float* __restrict__ b1,
    const float* __restrict__ m1, const float* __restrict__ v1,
    const float* __restrict__ g2, const float* __restrict__ b2,
    const float* __restrict__ m2, const float* __restrict__ v2,
    float* __restrict__ a)
{
    __shared__ float ain[128], y1[128];
    int tok = blockIdx.x;
    int c = threadIdx.x;
    ain[c] = a[tok * 128 + c];
    __syncthreads();
    float s = 0.f;
    #pragma unroll 8
    for (int k = 0; k < 128; ++k) s += ain[k] * W1[k * 128 + c];
    s = (s - m1[c]) * rsqrtf(v1[c] + 1e-3f) * g1[c] + b1[c];
    y1[c] = fmaxf(s, 0.f);
    __syncthreads();
    float s2 = 0.f;
    #pragma unroll 8
    for (int k = 0; k < 128; ++k) s2 += y1[k] * W2[k * 128 + c];
    s2 = (s2 - m2[c]) * rsqrtf(v2[c] + 1e-3f) * g2[c] + b2[c];
    a[tok * 128 + c] = ain[c] + s2;
}

// ---------------- cond out matmul: a @ mr_out_w + mr_out_b ----------------
__global__ __launch_bounds__(128) void outmat_kernel(
    const float* __restrict__ W, const float* __restrict__ bias,
    const float* __restrict__ a, float* __restrict__ out)
{
    __shared__ float ain[128];
    int tok = blockIdx.x;
    int c = threadIdx.x;
    ain[c] = a[tok * 128 + c];
    __syncthreads();
    float s = 0.f;
    #pragma unroll 8
    for (int k = 0; k < 128; ++k) s += ain[k] * W[k * 128 + c];
    out[tok * 128 + c] = s + bias[c];
}

// ---------------- big fused GEMM ----------------
// modes: 0=Wi (K=113, gather audio/mels_up/a0, out f32 x)
//        1=Wx0 (K=512, out bf16 xp, bias2=bh cols<1024)
//        2=Wx1 (K=544 = x|a1, out bf16 xp, bias2=bh cols<1024)
//        3=Wd0 (K=544 = x|a2, epilogue relu+resid, out f32)
//        4=Wd1 (K=544 = x3|a3, epilogue relu+resid, out f32)
__device__ __forceinline__ float fetchA(int mode, int row, int k, int K,
    const float* audio, const float* melsup, const float* cond, const float* xA)
{
    if (k >= K) return 0.f;
    int b = row / T_SEQ;
    int t = row - b * T_SEQ;
    if (mode == 0) {
        if (k == 0) return audio[(size_t)b * (T_SEQ + 1) + t];
        if (k < 81) return melsup[((size_t)b * 11264 + 512 + t) * 80 + (k - 1)];
        return cond[((size_t)b * 40 + (t >> 8)) * 128 + (k - 81)];
    }
    if (k < 512) return xA[(size_t)row * 512 + k];
    int co = (mode == 2) ? 32 : (mode == 3) ? 64 : 96;
    return cond[((size_t)b * 40 + (t >> 8)) * 128 + co + (k - 512)];
}

__global__ __launch_bounds__(256) void gemm_big(
    int mode, int N, int K,
    const float* __restrict__ W, const float* __restrict__ bias1,
    const float* __restrict__ bias2,
    const float* __restrict__ audio, const float* __restrict__ melsup,
    const float* __restrict__ cond, const float* __restrict__ xA,
    const float* __restrict__ resid, float* __restrict__ outF,
    __hip_bfloat16* __restrict__ outB)
{
    __shared__ float As[16][68];
    __shared__ float Bs[16][68];
    const int tid = threadIdx.x;
    const int row0 = blockIdx.y * 64;
    const int col0 = blockIdx.x * 64;
    const int tx = tid & 15, ty = tid >> 4;
    float acc[4][4] = {};
    const int nkt = (K + 15) >> 4;
    for (int kt = 0; kt < nkt; ++kt) {
        const int kb = kt << 4;
        #pragma unroll
        for (int l = 0; l < 4; ++l) {
            int k = (tid >> 6) + l * 4;
            int m = tid & 63;
            float bv = 0.f;
            if (kb + k < K) bv = W[(size_t)(kb + k) * N + col0 + m];
            Bs[k][m] = bv;
        }
        if (mode != 0) {
            int m = tid >> 2, kq = tid & 3;
            int row = row0 + m;
            int k = kb + kq * 4;
            if (k + 3 < 512) {
                float4 v = *reinterpret_cast<const float4*>(xA + (size_t)row * 512 + k);
                As[kq * 4 + 0][m] = v.x; As[kq * 4 + 1][m] = v.y;
                As[kq * 4 + 2][m] = v.z; As[kq * 4 + 3][m] = v.w;
            } else {
                #pragma unroll
                for (int i = 0; i < 4; ++i)
                    As[kq * 4 + i][m] = fetchA(mode, row, k + i, K, audio, melsup, cond, xA);
            }
        } else {
            #pragma unroll
            for (int l = 0; l < 4; ++l) {
                int k = (tid >> 6) + l * 4;
                int m = tid & 63;
                As[k][m] = fetchA(0, row0 + m, kb + k, K, audio, melsup, cond, xA);
            }
        }
        __syncthreads();
        #pragma unroll
        for (int k = 0; k < 16; ++k) {
            float a0 = As[k][(ty << 2) + 0], a1 = As[k][(ty << 2) + 1];
            float a2 = As[k][(ty << 2) + 2], a3 = As[k][(ty << 2) + 3];
            float b0 = Bs[k][(tx << 2) + 0], b1 = Bs[k][(tx << 2) + 1];
            float b2 = Bs[k][(tx << 2) + 2], b3 = Bs[k][(tx << 2) + 3];
            acc[0][0] += a0 * b0; acc[0][1] += a0 * b1; acc[0][2] += a0 * b2; acc[0][3] += a0 * b3;
            acc[1][0] += a1 * b0; acc[1][1] += a1 * b1; acc[1][2] += a1 * b2; acc[1][3] += a1 * b3;
            acc[2][0] += a2 * b0; acc[2][1] += a2 * b1; acc[2][2] += a2 * b2; acc[2][3] += a2 * b3;
            acc[3][0] += a3 * b0; acc[3][1] += a3 * b1; acc[3][2] += a3 * b2; acc[3][3] += a3 * b3;
        }
        __syncthreads();
    }
    #pragma unroll
    for (int i = 0; i < 4; ++i) {
        int row = row0 + (ty << 2) + i;
        #pragma unroll
        for (int jt = 0; jt < 4; ++jt) {
            int col = col0 + (tx << 2) + jt;
            float v = acc[i][jt] + bias1[col];
            if (bias2 && col < 1024) v += bias2[col];
            if (mode == 0) {
                outF[(size_t)row * N + col] = v;
            } else if (mode <= 2) {
                outB[(size_t)row * 1536 + col] = __float2bfloat16(v);
            } else {
                v = fmaxf(v, 0.f) + resid[(size_t)row * 512 + col];
                outF[(size_t)row * 512 + col] = v;
            }
        }
    }
}

// ---------------- persistent GRU layer (pair-sync version) ----------------
// 64 WGs x 512 threads = 8 waves. Wave jj owns hidden unit j = wg*8+jj.
// Lane covers k-slice of 8; holds 24 weight floats in registers; accumulates
// all 4 batches (96 FMAs) then 6-level shfl_xor butterfly.
// Sync: h values published as {u32 tag=t+1, f32 h} 8B relaxed agent atomics
// into ping-pong pair buffers; consumers poll pairs directly (no flags, no
// fences). 2048 pairs polled cooperatively (4/thread), shared via LDS.
__global__ __launch_bounds__(512, 1) void gru_layer(
    const float* __restrict__ Wh,             // (512,1536)
    const float* __restrict__ bh,             // (1536) - only [1024:1536) used
    const __hip_bfloat16* __restrict__ xp,    // (B*T,1536)  x@Wx+bx (+bh z/r)
    float* __restrict__ xio,                  // (B*T,512) in: x, out: x+h
    unsigned long long* __restrict__ hpair,   // [2][4][512] {tag,h}, memset 0
    int T)
{
    const int tid = threadIdx.x;
    const int wg = blockIdx.x;
    const int jj = tid >> 6;
    const int lane = tid & 63;
    const int j = wg * 8 + jj;
    const int k0 = lane * 8;

    __shared__ float h_sh[2048];              // [b][512]

    float wz[8], wr[8], wh3[8];
    #pragma unroll
    for (int i = 0; i < 8; ++i) {
        const float* rowp = Wh + (size_t)(k0 + i) * 1536 + j;
        wz[i]  = rowp[0];
        wr[i]  = rowp[512];
        wh3[i] = rowp[1024];
    }
    const float bhh = bh[1024 + j];

    // lanes 0-3 are per-batch leads (b = lane); prefetch t=0 gate inputs
    float xz_c = 0.f, xr_c = 0.f, xh_c = 0.f, xv_c = 0.f;
    if (lane < 4) {
        const __hip_bfloat16* p = xp + ((size_t)lane * T) * 1536;
        xz_c = __bfloat162float(p[j]);
        xr_c = __bfloat162float(p[512 + j]);
        xh_c = __bfloat162float(p[1024 + j]);
        xv_c = xio[((size_t)lane * T) * 512 + j];
    }

    for (int t = 0; t < T; ++t) {
        // ---- poll own 4 pairs (data+tag in one 8B atomic), share via LDS ----
        const unsigned long long* src =
            hpair + (size_t)(t & 1) * 2048 + (size_t)tid * 4;
        const unsigned utag = (unsigned)t;
        float hv0, hv1, hv2, hv3;
        {
            bool d0 = false, d1 = false, d2 = false, d3 = false;
            do {
                if (!d0) { unsigned long long u = __hip_atomic_load(src + 0, __ATOMIC_RELAXED, __HIP_MEMORY_SCOPE_AGENT);
                           if ((unsigned)(u >> 32) == utag) { hv0 = __uint_as_float((unsigned)u); d0 = true; } }
                if (!d1) { unsigned long long u = __hip_atomic_load(src + 1, __ATOMIC_RELAXED, __HIP_MEMORY_SCOPE_AGENT);
                           if ((unsigned)(u >> 32) == utag) { hv1 = __uint_as_float((unsigned)u); d1 = true; } }
                if (!d2) { unsigned long long u = __hip_atomic_load(src + 2, __ATOMIC_RELAXED, __HIP_MEMORY_SCOPE_AGENT);
                           if ((unsigned)(u >> 32) == utag) { hv2 = __uint_as_float((unsigned)u); d2 = true; } }
                if (!d3) { unsigned long long u = __hip_atomic_load(src + 3, __ATOMIC_RELAXED, __HIP_MEMORY_SCOPE_AGENT);
                           if ((unsigned)(u >> 32) == utag) { hv3 = __uint_as_float((unsigned)u); d3 = true; } }
            } while (!(d0 && d1 && d2 && d3));
        }
        *reinterpret_cast<float4*>(h_sh + tid * 4) = make_float4(hv0, hv1, hv2, hv3);
        __syncthreads();

        // ---- 96 FMAs: 3 gates x 4 batches over k-slice of 8 ----
        float az[4], ar[4], ah[4];
        #pragma unroll
        for (int b = 0; b < 4; ++b) {
            const float* hp = h_sh + b * 512 + k0;
            float4 ha = *reinterpret_cast<const float4*>(hp);
            float4 hb = *reinterpret_cast<const float4*>(hp + 4);
            az[b] = ha.x*wz[0] + ha.y*wz[1] + ha.z*wz[2] + ha.w*wz[3]
                  + hb.x*wz[4] + hb.y*wz[5] + hb.z*wz[6] + hb.w*wz[7];
            ar[b] = ha.x*wr[0] + ha.y*wr[1] + ha.z*wr[2] + ha.w*wr[3]
                  + hb.x*wr[4] + hb.y*wr[5] + hb.z*wr[6] + hb.w*wr[7];
            ah[b] = ha.x*wh3[0] + ha.y*wh3[1] + ha.z*wh3[2] + ha.w*wh3[3]
                  + hb.x*wh3[4] + hb.y*wh3[5] + hb.z*wh3[6] + hb.w*wh3[7];
        }
        // ---- butterfly reduce over 64 lanes (all lanes end with full sums) ----
        #pragma unroll
        for (int m = 1; m < 64; m <<= 1) {
            #pragma unroll
            for (int b = 0; b < 4; ++b) {
                az[b] += __shfl_xor(az[b], m);
                ar[b] += __shfl_xor(ar[b], m);
                ah[b] += __shfl_xor(ah[b], m);
            }
        }

        // ---- lanes 0-3: gates + publish for batch b=lane ----
        float azs = lane == 0 ? az[0] : lane == 1 ? az[1] : lane == 2 ? az[2] : az[3];
        float ars = lane == 0 ? ar[0] : lane == 1 ? ar[1] : lane == 2 ? ar[2] : ar[3];
        float ahs = lane == 0 ? ah[0] : lane == 1 ? ah[1] : lane == 2 ? ah[2] : ah[3];
        if (lane < 4) {
            float z = 1.f / (1.f + __expf(-(xz_c + azs)));
            float r = 1.f / (1.f + __expf(-(xr_c + ars)));
            float e2 = __expf(-2.f * (xh_c + r * (ahs + bhh)));
            float hh = (1.f - e2) / (1.f + e2);
            float hprev = h_sh[lane * 512 + j];
            float hn = z * hprev + (1.f - z) * hh;
            unsigned long long pv =
                ((unsigned long long)(unsigned)(t + 1) << 32) |
                (unsigned long long)__float_as_uint(hn);
            __hip_atomic_store(hpair + (size_t)((t + 1) & 1) * 2048 + (size_t)lane * 512 + j,
                               pv, __ATOMIC_RELAXED, __HIP_MEMORY_SCOPE_AGENT);
            xio[((size_t)lane * T + t) * 512 + j] = xv_c + hn;
            if (t + 1 < T) {
                const __hip_bfloat16* p = xp + ((size_t)lane * T + (t + 1)) * 1536;
                xz_c = __bfloat162float(p[j]);
                xr_c = __bfloat162float(p[512 + j]);
                xh_c = __bfloat162float(p[1024 + j]);
                xv_c = xio[((size_t)lane * T + (t + 1)) * 512 + j];
            }
        }
        // no end-of-step barrier needed: next poll transitively orders h_sh reuse
    }
}

// ---------------- final projection: logits = x @ Wp + bp ----------------
__global__ __launch_bounds__(256) void wp_kernel(
    const float* __restrict__ x, const float* __restrict__ Wp,
    const float* __restrict__ bp, float* __restrict__ out)
{
    int r = threadIdx.x >> 5, c = threadIdx.x & 31;
    size_t row = (size_t)blockIdx.x * 8 + r;
    if (c >= 30) return;
    const float* xr = x + row * 512;
    float acc = 0.f;
    #pragma unroll 8
    for (int k = 0; k < 512; ++k) acc += xr[k] * Wp[k * 30 + c];
    out[row * 30 + c] = acc + bp[c];
}

extern "C" void kernel_launch(void* const* d_in, const int* in_sizes, int n_in,
                              void* d_out, int out_size, void* d_ws, size_t ws_size,
                              hipStream_t stream)
{
    const float* audios = (const float*)d_in[0];
    const float* mels   = (const float*)d_in[1];
    const float* w_mel0 = (const float*)d_in[2];
    const float* w_mel1 = (const float*)d_in[3];
    const float* w_mel2 = (const float*)d_in[4];
    const float* conv0w = (const float*)d_in[5];
    const float* bn0g = (const float*)d_in[6];
    const float* bn0b = (const float*)d_in[7];
    const float* bn0m = (const float*)d_in[8];
    const float* bn0v = (const float*)d_in[9];
    const float* r_w1   = (const float*)d_in[10];
    const float* r_bn1g = (const float*)d_in[11];
    const float* r_bn1b = (const float*)d_in[12];
    const float* r_bn1m = (const float*)d_in[13];
    const float* r_bn1v = (const float*)d_in[14];
    const float* r_w2   = (const float*)d_in[15];
    const float* r_bn2g = (const float*)d_in[16];
    const float* r_bn2b = (const float*)d_in[17];
    const float* r_bn2m = (const float*)d_in[18];
    const float* r_bn2v = (const float*)d_in[19];
    const float* mr_out_w = (const float*)d_in[20];
    const float* mr_out_b = (const float*)d_in[21];
    const float* Wi = (const float*)d_in[22];
    const float* bi = (const float*)d_in[23];
    const float* Wx0 = (const float*)d_in[24];
    const float* Wh0 = (const float*)d_in[25];
    const float* bx0 = (const float*)d_in[26];
    const float* bh0 = (const float*)d_in[27];
    const float* Wx1 = (const float*)d_in[28];
    const float* Wh1 = (const float*)d_in[29];
    const float* bx1 = (const float*)d_in[30];
    const float* bh1 = (const float*)d_in[31];
    const float* Wd0 = (const float*)d_in[32];
    const float* bd0 = (const float*)d_in[33];
    const float* Wd1 = (const float*)d_in[34];
    const float* bd1 = (const float*)d_in[35];
    const float* Wp = (const float*)d_in[36];
    const float* bp = (const float*)d_in[37];

    char* ws = (char*)d_ws;
    size_t off = 0;
    auto alloc = [&](size_t n) { size_t r = off; off += (n + 255) & ~(size_t)255; return r; };
    const size_t M = 4 * (size_t)T_SEQ;                      // 40960
    size_t xp_off = alloc(M * 1536 * 2);                     // bf16 xp; reused as f32 x3
    size_t x_off  = alloc(M * 512 * 4);                      // f32 x
    size_t s1_off = alloc((size_t)4 * 176 * 80 * 4);
    size_t s2_off = alloc((size_t)4 * 1408 * 80 * 4);
    size_t s3_off = alloc((size_t)4 * 11264 * 80 * 4);
    size_t ca_off = alloc((size_t)160 * 128 * 4);
    size_t cf_off = alloc((size_t)160 * 128 * 4);
    size_t hp_off = alloc(2 * 4 * 512 * 8);                  // pair buffers (32KB)

    __hip_bfloat16* xp = (__hip_bfloat16*)(ws + xp_off);
    float* x3   = (float*)(ws + xp_off);
    float* xbuf = (float*)(ws + x_off);
    float* st1  = (float*)(ws + s1_off);
    float* st2  = (float*)(ws + s2_off);
    float* st3  = (float*)(ws + s3_off);
    float* conda = (float*)(ws + ca_off);
    float* condf = (float*)(ws + cf_off);
    unsigned long long* hpair = (unsigned long long*)(ws + hp_off);
    float* outp = (float*)d_out;

    // 1-3: mel upsampling
    {
        int tot1 = 4 * 176 * 80;
        upsample_kernel<<<(tot1 + 255) / 256, 256, 0, stream>>>(mels, st1, w_mel0, 4, 44, 176, 2, 9);
        int tot2 = 4 * 1408 * 80;
        upsample_kernel<<<(tot2 + 255) / 256, 256, 0, stream>>>(st1, st2, w_mel1, 4, 176, 1408, 3, 17);
        int tot3 = 4 * 11264 * 80;
        upsample_kernel<<<(tot3 + 255) / 256, 256, 0, stream>>>(st2, st3, w_mel2, 4, 1408, 11264, 3, 17);
    }
    // 4-6: conditioning net
    conv0_kernel<<<160, 128, 0, stream>>>(mels, conv0w, bn0g, bn0b, bn0m, bn0v, conda);
    for (int i = 0; i < 10; ++i) {
        resblock_kernel<<<160, 128, 0, stream>>>(
            r_w1 + (size_t)i * 128 * 128, r_w2 + (size_t)i * 128 * 128,
            r_bn1g + i * 128, r_bn1b + i * 128, r_bn1m + i * 128, r_bn1v + i * 128,
            r_bn2g + i * 128, r_bn2b + i * 128, r_bn2m + i * 128, r_bn2v + i * 128,
            conda);
    }
    outmat_kernel<<<160, 128, 0, stream>>>(mr_out_w, mr_out_b, conda, condf);

    dim3 blk(256);
    // 7: x = concat(audio, mels_up, a0) @ Wi + bi
    gemm_big<<<dim3(8, 640), blk, 0, stream>>>(0, 512, 113, Wi, bi, nullptr,
        audios, st3, condf, nullptr, nullptr, xbuf, nullptr);
    // 8: xp0 = x @ Wx0 + bx0 (+bh0 z/r)
    gemm_big<<<dim3(24, 640), blk, 0, stream>>>(1, 1536, 512, Wx0, bx0, bh0,
        nullptr, nullptr, condf, xbuf, nullptr, nullptr, xp);
    // 9: GRU0
    hipMemsetAsync(ws + hp_off, 0, 2 * 4 * 512 * 8, stream);
    gru_layer<<<GRU_NWG, 512, 0, stream>>>(Wh0, bh0, xp, xbuf, hpair, T_SEQ);
    // 10: xp1 = concat(x1, a1) @ Wx1 + bx1 (+bh1 z/r)
    gemm_big<<<dim3(24, 640), blk, 0, stream>>>(2, 1536, 544, Wx1, bx1, bh1,
        nullptr, nullptr, condf, xbuf, nullptr, nullptr, xp);
    // 11: GRU1
    hipMemsetAsync(ws + hp_off, 0, 2 * 4 * 512 * 8, stream);
    gru_layer<<<GRU_NWG, 512, 0, stream>>>(Wh1, bh1, xp, xbuf, hpair, T_SEQ);
    // 12: x3 = relu(concat(x2, a2) @ Wd0 + bd0) + x2
    gemm_big<<<dim3(8, 640), blk, 0, stream>>>(3, 512, 544, Wd0, bd0, nullptr,
        nullptr, nullptr, condf, xbuf, xbuf, x3, nullptr);
    // 13: x4 = relu(concat(x3, a3) @ Wd1 + bd1) + x3
    gemm_big<<<dim3(8, 640), blk, 0, stream>>>(4, 512, 544, Wd1, bd1, nullptr,
        nullptr, nullptr, condf, x3, x3, xbuf, nullptr);
    // 14: logits
    wp_kernel<<<5120, 256, 0, stream>>>(xbuf, Wp, bp, outp);
}